// Round 3
// baseline (177.559 us; speedup 1.0000x reference)
//
#include <hip/hip_runtime.h>
#include <math.h>

// Problem constants
#define PB 8
#define PT 12
#define PN 307
#define NP 320                      // padded N (rows and cols) for MFMA tiling
#define SCALE 0.35355339059327373f  // 1/sqrt(8)

typedef short bf16x8 __attribute__((ext_vector_type(8)));
typedef float f32x4  __attribute__((ext_vector_type(4)));

__device__ __forceinline__ unsigned short f32_to_bf16(float v) {
    unsigned u = __float_as_uint(v);
    u += 0x7FFFu + ((u >> 16) & 1u);   // RNE
    return (unsigned short)(u >> 16);
}

// ---------------------------------------------------------------------------
// Kernel A: Q/K projection -> bf16, row-major [bt][NP][64], pad rows zeroed.
// Grid: 96 bt * 5 chunks of 64 rows. Block 256.
// Each thread: e = tid&63, 16 rows starting at (tid>>6)*16.
// ---------------------------------------------------------------------------
__global__ __launch_bounds__(256) void qk_proj_kernel(
    const float* __restrict__ x,
    const float* __restrict__ Wq, const float* __restrict__ bq,
    const float* __restrict__ Wk, const float* __restrict__ bk,
    unsigned short* __restrict__ qws, unsigned short* __restrict__ kws)
{
    __shared__ float wqT[64 * 65];   // [c][e]
    __shared__ float wkT[64 * 65];
    __shared__ float xs[64][68];     // [c][nl]

    const int tid = threadIdx.x;
    const int chunk = blockIdx.x % 5;
    const int bt = blockIdx.x / 5;
    const int b = bt / PT, t = bt % PT;
    const int n0 = chunk * 64;

    for (int idx = tid; idx < 4096; idx += 256) {
        int e = idx >> 6, c = idx & 63;
        wqT[c * 65 + e] = Wq[idx];
        wkT[c * 65 + e] = Wk[idx];
    }
    for (int idx = tid; idx < 4096; idx += 256) {
        int c = idx >> 6, nl = idx & 63;     // lanes consecutive in nl -> coalesced
        int n = n0 + nl;
        xs[c][nl] = (n < PN) ? x[((b * 64 + c) * PT + t) * PN + n] : 0.f;
    }
    __syncthreads();

    const int e  = tid & 63;
    const int rg = (tid >> 6) * 16;

    float accq[16], acck[16];
    const float bqv = bq[e], bkv = bk[e];
    #pragma unroll
    for (int j = 0; j < 16; ++j) { accq[j] = bqv; acck[j] = bkv; }

    #pragma unroll 4
    for (int c = 0; c < 64; ++c) {
        const float wq = wqT[c * 65 + e];
        const float wk = wkT[c * 65 + e];
        const float4* xp = (const float4*)&xs[c][rg];   // wave-uniform -> broadcast
        float4 x0 = xp[0], x1 = xp[1], x2 = xp[2], x3 = xp[3];
        float xr[16] = {x0.x, x0.y, x0.z, x0.w, x1.x, x1.y, x1.z, x1.w,
                        x2.x, x2.y, x2.z, x2.w, x3.x, x3.y, x3.z, x3.w};
        #pragma unroll
        for (int j = 0; j < 16; ++j) {
            accq[j] = fmaf(xr[j], wq, accq[j]);
            acck[j] = fmaf(xr[j], wk, acck[j]);
        }
    }

    #pragma unroll
    for (int j = 0; j < 16; ++j) {
        const int n = n0 + rg + j;
        const bool v = (n < PN);
        qws[((size_t)bt * NP + n) * 64 + e] = v ? f32_to_bf16(accq[j]) : (unsigned short)0;
        kws[((size_t)bt * NP + n) * 64 + e] = v ? f32_to_bf16(acck[j]) : (unsigned short)0;
    }
}

// ---------------------------------------------------------------------------
// Kernel B: S = Q K^T / sqrt(8) via MFMA, mask, softmax over m, store.
// Grid: 96 bt * 5 chunks of 64 rows. Block 256 = 4 waves; wave owns 16 rows
// x 320 cols = 20 C-tiles of 16x16.
// K tile staged ONCE per block into LDS in *fragment order*:
//   kT[((ct*2+ks)*64 + lane)*8 .. +8) = lane's B-fragment for tile ct, kstep ks
// so the inner loop's ds_read_b128 is linear & conflict-free, and no giant
// in-flight global load set inflates VGPR pressure (R2's failure mode).
// ---------------------------------------------------------------------------
__global__ __launch_bounds__(256) void attn_kernel(
    const unsigned short* __restrict__ qws,
    const unsigned short* __restrict__ kws,
    const int* __restrict__ mask,
    float* __restrict__ out)
{
    __shared__ unsigned short kT[40 * 64 * 8];   // 40 KB: [ct*2+ks][lane][8]

    const int tid  = threadIdx.x;
    const int lane = tid & 63;
    const int wv   = tid >> 6;
    const int chunk = blockIdx.x % 5;
    const int bt    = blockIdx.x / 5;
    const int b     = bt / PT;
    const int n0    = chunk * 64 + wv * 16;  // wave's first row
    const int rlo   = lane & 15;             // A-row / B-col / C-col within tile
    const int kq    = lane >> 4;             // quad

    // ---- stage K [320][64] bf16 -> fragment-order LDS (2560 x 16B chunks)
    {
        const uint4* src = (const uint4*)(kws + (size_t)bt * NP * 64);
        uint4* dst = (uint4*)kT;
        #pragma unroll
        for (int i = 0; i < 10; ++i) {
            const int c16 = tid + 256 * i;       // global 16B-chunk index
            const int row = c16 >> 3;            // 0..319
            const int seg = c16 & 7;             // 16B segment within row
            const int ct  = row >> 4;
            const int rl  = row & 15;
            const int ks  = seg >> 2;
            const int kk  = seg & 3;
            dst[(ct * 2 + ks) * 64 + kk * 16 + rl] = src[c16];
        }
    }
    __syncthreads();

    // ---- A fragments straight from global (2 x 16B per lane)
    const bf16x8* qp = (const bf16x8*)(qws + ((size_t)bt * NP + n0 + rlo) * 64 + kq * 8);

    f32x4 acc[20] = {};
    #pragma unroll
    for (int ks = 0; ks < 2; ++ks) {
        const bf16x8 afr = qp[ks * 4];
        const bf16x8* kb = (const bf16x8*)kT + ks * 64 + lane;
        #pragma unroll 5
        for (int ct = 0; ct < 20; ++ct) {
            const bf16x8 bfr = kb[ct * 128];
            acc[ct] = __builtin_amdgcn_mfma_f32_16x16x32_bf16(afr, bfr, acc[ct], 0, 0, 0);
        }
    }

    // ---- softmax in C layout: elem (ct, r) = S[n0 + kq*4 + r][ct*16 + rlo]
    float mx[4] = {-INFINITY, -INFINITY, -INFINITY, -INFINITY};
    #pragma unroll
    for (int ct = 0; ct < 20; ++ct) {
        const int m = ct * 16 + rlo;
        const bool mval = (m < PN);
        #pragma unroll
        for (int r = 0; r < 4; ++r) {
            const int n  = n0 + kq * 4 + r;
            const int nn = (n < PN) ? n : (PN - 1);          // clamp: stay in-bounds
            float s;
            if (mval) {
                const int mk = mask[((size_t)b * PN + nn) * PN + m];
                s = mk ? acc[ct][r] * SCALE : -1e9f;
            } else {
                s = -INFINITY;                               // pad columns
            }
            acc[ct][r] = s;
            mx[r] = fmaxf(mx[r], s);
        }
    }
    #pragma unroll
    for (int off = 1; off <= 8; off <<= 1) {
        #pragma unroll
        for (int r = 0; r < 4; ++r) mx[r] = fmaxf(mx[r], __shfl_xor(mx[r], off));
    }

    float sum[4] = {0.f, 0.f, 0.f, 0.f};
    #pragma unroll
    for (int ct = 0; ct < 20; ++ct) {
        #pragma unroll
        for (int r = 0; r < 4; ++r) {
            const float p = __expf(acc[ct][r] - mx[r]);
            acc[ct][r] = p;
            sum[r] += p;
        }
    }
    #pragma unroll
    for (int off = 1; off <= 8; off <<= 1) {
        #pragma unroll
        for (int r = 0; r < 4; ++r) sum[r] += __shfl_xor(sum[r], off);
    }
    float inv[4];
    #pragma unroll
    for (int r = 0; r < 4; ++r) inv[r] = 1.0f / sum[r];

    #pragma unroll
    for (int ct = 0; ct < 20; ++ct) {
        const int m = ct * 16 + rlo;
        if (m < PN) {
            #pragma unroll
            for (int r = 0; r < 4; ++r) {
                const int n = n0 + kq * 4 + r;
                if (n < PN)
                    out[((size_t)bt * PN + n) * PN + m] = acc[ct][r] * inv[r];
            }
        }
    }
}

extern "C" void kernel_launch(void* const* d_in, const int* in_sizes, int n_in,
                              void* d_out, int out_size, void* d_ws, size_t ws_size,
                              hipStream_t stream) {
    const float* x  = (const float*)d_in[0];
    const int* mask = (const int*)d_in[1];
    const float* Wq = (const float*)d_in[2];
    const float* bq = (const float*)d_in[3];
    const float* Wk = (const float*)d_in[4];
    const float* bk = (const float*)d_in[5];
    float* out = (float*)d_out;

    // workspace: qws bf16 [96][320][64], kws bf16 [96][320][64]  (7.86 MB)
    unsigned short* qws = (unsigned short*)d_ws;
    unsigned short* kws = qws + (size_t)96 * NP * 64;

    qk_proj_kernel<<<dim3(96 * 5), dim3(256), 0, stream>>>(x, Wq, bq, Wk, bk, qws, kws);
    attn_kernel<<<dim3(96 * 5), dim3(256), 0, stream>>>(qws, kws, mask, out);
}

// Round 4
// 112.429 us; speedup vs baseline: 1.5793x; 1.5793x over previous
//
#include <hip/hip_runtime.h>
#include <math.h>

// Problem constants
#define PB 8
#define PT 12
#define PN 307
#define NP 320                      // padded N (rows and cols) for MFMA tiling
#define SCALE 0.35355339059327373f  // 1/sqrt(8)

typedef short bf16x8 __attribute__((ext_vector_type(8)));
typedef float f32x4  __attribute__((ext_vector_type(4)));

__device__ __forceinline__ unsigned short f32_to_bf16(float v) {
    unsigned u = __float_as_uint(v);
    u += 0x7FFFu + ((u >> 16) & 1u);   // RNE
    return (unsigned short)(u >> 16);
}

// ---------------------------------------------------------------------------
// Kernel A v3: Q/K projection -> bf16, row-major [bt][NP][64], pad rows zeroed.
// Grid: 96 bt * 10 chunks of 32 rows = 960 blocks (3.75/CU). Block 256.
// Each thread: e = tid&63, 8 rows starting at (tid>>6)*8; 16 fp32 accs.
// ---------------------------------------------------------------------------
__global__ __launch_bounds__(256) void qk_proj_kernel(
    const float* __restrict__ x,
    const float* __restrict__ Wq, const float* __restrict__ bq,
    const float* __restrict__ Wk, const float* __restrict__ bk,
    unsigned short* __restrict__ qws, unsigned short* __restrict__ kws)
{
    __shared__ float wqT[64 * 65];   // [c][e] = Wq[e][c]
    __shared__ float wkT[64 * 65];
    __shared__ float xs[64][36];     // [c][nl], stride 36 keeps float4 alignment

    const int tid = threadIdx.x;
    const int chunk = blockIdx.x % 10;
    const int bt = blockIdx.x / 10;
    const int b = bt / PT, t = bt % PT;
    const int n0 = chunk * 32;

    for (int idx = tid; idx < 4096; idx += 256) {
        int e = idx >> 6, c = idx & 63;
        wqT[c * 65 + e] = Wq[idx];
        wkT[c * 65 + e] = Wk[idx];
    }
    for (int idx = tid; idx < 2048; idx += 256) {
        int c = idx >> 5, nl = idx & 31;     // wave reads 2 rows of 128B, coalesced
        int n = n0 + nl;
        xs[c][nl] = (n < PN) ? x[((b * 64 + c) * PT + t) * PN + n] : 0.f;
    }
    __syncthreads();

    const int e  = tid & 63;
    const int rg = (tid >> 6) * 8;           // wave-uniform -> LDS broadcast reads

    float accq[8], acck[8];
    const float bqv = bq[e], bkv = bk[e];
    #pragma unroll
    for (int j = 0; j < 8; ++j) { accq[j] = bqv; acck[j] = bkv; }

    #pragma unroll 4
    for (int c = 0; c < 64; ++c) {
        const float wq = wqT[c * 65 + e];
        const float wk = wkT[c * 65 + e];
        const float4 x0 = *(const float4*)&xs[c][rg];
        const float4 x1 = *(const float4*)&xs[c][rg + 4];
        accq[0] = fmaf(x0.x, wq, accq[0]);  acck[0] = fmaf(x0.x, wk, acck[0]);
        accq[1] = fmaf(x0.y, wq, accq[1]);  acck[1] = fmaf(x0.y, wk, acck[1]);
        accq[2] = fmaf(x0.z, wq, accq[2]);  acck[2] = fmaf(x0.z, wk, acck[2]);
        accq[3] = fmaf(x0.w, wq, accq[3]);  acck[3] = fmaf(x0.w, wk, acck[3]);
        accq[4] = fmaf(x1.x, wq, accq[4]);  acck[4] = fmaf(x1.x, wk, acck[4]);
        accq[5] = fmaf(x1.y, wq, accq[5]);  acck[5] = fmaf(x1.y, wk, acck[5]);
        accq[6] = fmaf(x1.z, wq, accq[6]);  acck[6] = fmaf(x1.z, wk, acck[6]);
        accq[7] = fmaf(x1.w, wq, accq[7]);  acck[7] = fmaf(x1.w, wk, acck[7]);
    }

    #pragma unroll
    for (int j = 0; j < 8; ++j) {
        const int n = n0 + rg + j;
        const bool v = (n < PN);
        // lanes e=0..63 consecutive -> 128B contiguous store per row
        qws[((size_t)bt * NP + n) * 64 + e] = v ? f32_to_bf16(accq[j]) : (unsigned short)0;
        kws[((size_t)bt * NP + n) * 64 + e] = v ? f32_to_bf16(acck[j]) : (unsigned short)0;
    }
}

// ---------------------------------------------------------------------------
// Kernel B (R2-proven version): S = Q K^T / sqrt(8) via MFMA, mask, softmax.
// Grid: 96 bt * 5 chunks of 64 rows. Block 256 = 4 waves; wave owns 16 rows
// x 320 cols = 20 C-tiles of 16x16. No LDS, no barriers: fragments loaded
// straight from global as ushort8; all 4 waves read identical B-fragment
// addresses -> L1/L2 broadcast. (R3's LDS staging regressed 27->92 us.)
// ---------------------------------------------------------------------------
__global__ __launch_bounds__(256) void attn_kernel(
    const unsigned short* __restrict__ qws,
    const unsigned short* __restrict__ kws,
    const int* __restrict__ mask,
    float* __restrict__ out)
{
    const int tid  = threadIdx.x;
    const int lane = tid & 63;
    const int wv   = tid >> 6;
    const int chunk = blockIdx.x % 5;
    const int bt    = blockIdx.x / 5;
    const int b     = bt / PT;
    const int n0    = chunk * 64 + wv * 16;  // wave's first row
    const int rlo   = lane & 15;             // A-row / B-col / C-col within tile
    const int kq    = lane >> 4;             // quad

    f32x4 acc[20] = {};

    const bf16x8* qp = (const bf16x8*)(qws + ((size_t)bt * NP + n0 + rlo) * 64 + kq * 8);
    const unsigned short* kbase0 = kws + ((size_t)bt * NP + rlo) * 64 + kq * 8;

    #pragma unroll
    for (int ks = 0; ks < 2; ++ks) {
        const bf16x8 afr = qp[ks * 4];                       // +32 halfwords per kstep
        const unsigned short* kb = kbase0 + ks * 32;
        #pragma unroll
        for (int ct = 0; ct < 20; ++ct) {
            const bf16x8 bfr = *(const bf16x8*)(kb + (size_t)ct * 16 * 64);
            acc[ct] = __builtin_amdgcn_mfma_f32_16x16x32_bf16(afr, bfr, acc[ct], 0, 0, 0);
        }
    }

    // ---- softmax in C layout: elem (ct, r) = S[n0 + kq*4 + r][ct*16 + rlo]
    float mx[4] = {-INFINITY, -INFINITY, -INFINITY, -INFINITY};
    #pragma unroll
    for (int ct = 0; ct < 20; ++ct) {
        const int m = ct * 16 + rlo;
        const bool mval = (m < PN);
        #pragma unroll
        for (int r = 0; r < 4; ++r) {
            const int n  = n0 + kq * 4 + r;
            const int nn = (n < PN) ? n : (PN - 1);          // clamp: stay in-bounds
            float s;
            if (mval) {
                const int mk = mask[((size_t)b * PN + nn) * PN + m];
                s = mk ? acc[ct][r] * SCALE : -1e9f;
            } else {
                s = -INFINITY;                               // pad columns
            }
            acc[ct][r] = s;
            mx[r] = fmaxf(mx[r], s);
        }
    }
    #pragma unroll
    for (int off = 1; off <= 8; off <<= 1) {
        #pragma unroll
        for (int r = 0; r < 4; ++r) mx[r] = fmaxf(mx[r], __shfl_xor(mx[r], off));
    }

    float sum[4] = {0.f, 0.f, 0.f, 0.f};
    #pragma unroll
    for (int ct = 0; ct < 20; ++ct) {
        #pragma unroll
        for (int r = 0; r < 4; ++r) {
            const float p = __expf(acc[ct][r] - mx[r]);
            acc[ct][r] = p;
            sum[r] += p;
        }
    }
    #pragma unroll
    for (int off = 1; off <= 8; off <<= 1) {
        #pragma unroll
        for (int r = 0; r < 4; ++r) sum[r] += __shfl_xor(sum[r], off);
    }
    float inv[4];
    #pragma unroll
    for (int r = 0; r < 4; ++r) inv[r] = 1.0f / sum[r];

    #pragma unroll
    for (int ct = 0; ct < 20; ++ct) {
        const int m = ct * 16 + rlo;
        if (m < PN) {
            #pragma unroll
            for (int r = 0; r < 4; ++r) {
                const int n = n0 + kq * 4 + r;
                if (n < PN)
                    out[((size_t)bt * PN + n) * PN + m] = acc[ct][r] * inv[r];
            }
        }
    }
}

extern "C" void kernel_launch(void* const* d_in, const int* in_sizes, int n_in,
                              void* d_out, int out_size, void* d_ws, size_t ws_size,
                              hipStream_t stream) {
    const float* x  = (const float*)d_in[0];
    const int* mask = (const int*)d_in[1];
    const float* Wq = (const float*)d_in[2];
    const float* bq = (const float*)d_in[3];
    const float* Wk = (const float*)d_in[4];
    const float* bk = (const float*)d_in[5];
    float* out = (float*)d_out;

    // workspace: qws bf16 [96][320][64], kws bf16 [96][320][64]  (7.86 MB)
    unsigned short* qws = (unsigned short*)d_ws;
    unsigned short* kws = qws + (size_t)96 * NP * 64;

    qk_proj_kernel<<<dim3(96 * 10), dim3(256), 0, stream>>>(x, Wq, bq, Wk, bk, qws, kws);
    attn_kernel<<<dim3(96 * 5), dim3(256), 0, stream>>>(qws, kws, mask, out);
}

// Round 5
// 108.804 us; speedup vs baseline: 1.6319x; 1.0333x over previous
//
#include <hip/hip_runtime.h>
#include <math.h>

// Problem constants
#define PB 8
#define PT 12
#define PN 307
#define NP 320                      // padded N for MFMA tiling
#define SCALE 0.35355339059327373f  // 1/sqrt(8)

typedef short bf16x8 __attribute__((ext_vector_type(8)));
typedef float f32x4  __attribute__((ext_vector_type(4)));
// 4-byte-aligned vectors for rows whose base is only 4B-aligned (307-stride)
typedef int   i32x4u __attribute__((ext_vector_type(4), aligned(4)));
typedef float f32x4u __attribute__((ext_vector_type(4), aligned(4)));

__device__ __forceinline__ unsigned short f32_to_bf16(float v) {
    unsigned u = __float_as_uint(v);
    u += 0x7FFFu + ((u >> 16) & 1u);   // RNE
    return (unsigned short)(u >> 16);
}

__device__ __forceinline__ bf16x8 pack8(float4 lo, float4 hi) {
    bf16x8 r;
    r[0] = (short)f32_to_bf16(lo.x); r[1] = (short)f32_to_bf16(lo.y);
    r[2] = (short)f32_to_bf16(lo.z); r[3] = (short)f32_to_bf16(lo.w);
    r[4] = (short)f32_to_bf16(hi.x); r[5] = (short)f32_to_bf16(hi.y);
    r[6] = (short)f32_to_bf16(hi.z); r[7] = (short)f32_to_bf16(hi.w);
    return r;
}

// ---------------------------------------------------------------------------
// Kernel A (MFMA projection, no LDS, no barriers):
//   q[n][e] = sum_c xT[n][c] * Wq[e][c] + bq[e]   (same for k)
// MFMA mapping (validated in R2 attn): D row i <- A's lane&15, D col j <- B's
// lane&15; C elem = D[kq*4+r][lane&15].
// Grid: 96 bt * 10 chunks of 32 rows = 960 blocks; block 128 = 2 waves,
// each wave owns 16 n-rows x all 64 e.
// ---------------------------------------------------------------------------
__global__ __launch_bounds__(128) void qk_proj_kernel(
    const float* __restrict__ x,
    const float* __restrict__ Wq, const float* __restrict__ bq,
    const float* __restrict__ Wk, const float* __restrict__ bk,
    unsigned short* __restrict__ qws, unsigned short* __restrict__ kws)
{
    const int tid  = threadIdx.x;
    const int lane = tid & 63;
    const int wv   = tid >> 6;
    const int chunk = blockIdx.x % 10;
    const int bt    = blockIdx.x / 10;
    const int b = bt / PT, t = bt % PT;
    const int rlo = lane & 15;
    const int kq  = lane >> 4;
    const int n0  = chunk * 32 + wv * 16;        // wave's n-tile base

    // A fragments: xT[n][c], n = n0+rlo (clamped for loads), c = ks*32+kq*8+j
    const int nn = min(n0 + rlo, PN - 1);
    const float* xrow = x + ((size_t)b * 64 * PT + t) * PN + nn;  // + c*PT*PN
    bf16x8 a[2];
    #pragma unroll
    for (int ks = 0; ks < 2; ++ks) {
        #pragma unroll
        for (int j = 0; j < 8; ++j) {
            const int c = ks * 32 + kq * 8 + j;
            a[ks][j] = (short)f32_to_bf16(xrow[(size_t)c * PT * PN]);
        }
    }

    // B fragments: W rows (e = et*16+rlo), float4 loads are L1/L2-hot
    f32x4 accq[4] = {}, acck[4] = {};
    #pragma unroll
    for (int et = 0; et < 4; ++et) {
        const float* wq_r = Wq + (size_t)(et * 16 + rlo) * 64 + kq * 8;
        const float* wk_r = Wk + (size_t)(et * 16 + rlo) * 64 + kq * 8;
        #pragma unroll
        for (int ks = 0; ks < 2; ++ks) {
            const bf16x8 bqf = pack8(*(const float4*)(wq_r + ks * 32),
                                     *(const float4*)(wq_r + ks * 32 + 4));
            const bf16x8 bkf = pack8(*(const float4*)(wk_r + ks * 32),
                                     *(const float4*)(wk_r + ks * 32 + 4));
            accq[et] = __builtin_amdgcn_mfma_f32_16x16x32_bf16(a[ks], bqf, accq[et], 0, 0, 0);
            acck[et] = __builtin_amdgcn_mfma_f32_16x16x32_bf16(a[ks], bkf, acck[et], 0, 0, 0);
        }
    }

    // Epilogue: bias + bf16 + store. Pad rows (n>=307) skipped; attn never
    // uses their values (masked / discarded lanes), only needs them in-bounds.
    #pragma unroll
    for (int et = 0; et < 4; ++et) {
        const int e = et * 16 + rlo;
        const float bqv = bq[e], bkv = bk[e];
        #pragma unroll
        for (int r = 0; r < 4; ++r) {
            const int n = n0 + kq * 4 + r;
            if (n < PN) {
                qws[((size_t)bt * NP + n) * 64 + e] = f32_to_bf16(accq[et][r] + bqv);
                kws[((size_t)bt * NP + n) * 64 + e] = f32_to_bf16(acck[et][r] + bkv);
            }
        }
    }
}

// ---------------------------------------------------------------------------
// Kernel B (swapped-operand attn): A=K, B=Q -> tiles hold S^T:
//   lane = (nl, kq): n = ng + nl fixed per lane; m = ct*16 + kq*4 + r.
// -> per-lane float4 output stores, int4 mask loads, softmax reduces
// within-lane then across quads (shfl_xor 16,32) only.
// Grid: 96 bt * 5 chunks of 64 n = 480 blocks; block 256 = 4 waves.
// K fragments identical across waves -> L1 broadcast (R2-proven pattern).
// ---------------------------------------------------------------------------
__global__ __launch_bounds__(256) void attn_kernel(
    const unsigned short* __restrict__ qws,
    const unsigned short* __restrict__ kws,
    const int* __restrict__ mask,
    float* __restrict__ out)
{
    const int tid  = threadIdx.x;
    const int lane = tid & 63;
    const int wv   = tid >> 6;
    const int chunk = blockIdx.x % 5;
    const int bt    = blockIdx.x / 5;
    const int b     = bt / PT;
    const int ng  = chunk * 64 + wv * 16;
    const int nl  = lane & 15;
    const int kq  = lane >> 4;
    const int n   = ng + nl;
    const int nn  = (n < PN) ? n : (PN - 1);     // clamp for mask row reads

    // B fragments (Q row n), 2 ksteps; reads of pad rows are in-bounds garbage
    const bf16x8* qp = (const bf16x8*)(qws + ((size_t)bt * NP + n) * 64 + kq * 8);
    // A fragments (K rows m-tile), shared across all 4 waves
    const unsigned short* kbase = kws + ((size_t)bt * NP + nl) * 64 + kq * 8;

    f32x4 acc[20] = {};
    #pragma unroll
    for (int ks = 0; ks < 2; ++ks) {
        const bf16x8 bqf = qp[ks * 4];
        const unsigned short* kb = kbase + ks * 32;
        #pragma unroll
        for (int ct = 0; ct < 20; ++ct) {
            const bf16x8 af = *(const bf16x8*)(kb + (size_t)ct * 16 * 64);
            acc[ct] = __builtin_amdgcn_mfma_f32_16x16x32_bf16(af, bqf, acc[ct], 0, 0, 0);
        }
    }

    // ---- mask + scale, running max (per-lane: one n, 80 m-values)
    const int* mrow = mask + ((size_t)b * PN + nn) * PN;
    float mx = -INFINITY;
    #pragma unroll
    for (int ct = 0; ct < 20; ++ct) {
        const int m0 = ct * 16 + kq * 4;
        const i32x4u mv = *(const i32x4u*)(mrow + m0);
        float sv[4];
        sv[0] = mv[0] ? acc[ct][0] * SCALE : -1e9f;
        sv[1] = mv[1] ? acc[ct][1] * SCALE : -1e9f;
        sv[2] = mv[2] ? acc[ct][2] * SCALE : -1e9f;
        sv[3] = mv[3] ? acc[ct][3] * SCALE : -1e9f;
        if (ct == 19) {                           // pad columns m >= 307
            #pragma unroll
            for (int r = 0; r < 4; ++r)
                if (m0 + r >= PN) sv[r] = -INFINITY;
        }
        #pragma unroll
        for (int r = 0; r < 4; ++r) { acc[ct][r] = sv[r]; mx = fmaxf(mx, sv[r]); }
    }
    mx = fmaxf(mx, __shfl_xor(mx, 16));
    mx = fmaxf(mx, __shfl_xor(mx, 32));

    float sum = 0.f;
    #pragma unroll
    for (int ct = 0; ct < 20; ++ct) {
        #pragma unroll
        for (int r = 0; r < 4; ++r) {
            const float p = __expf(acc[ct][r] - mx);
            acc[ct][r] = p;
            sum += p;
        }
    }
    sum += __shfl_xor(sum, 16);
    sum += __shfl_xor(sum, 32);
    const float inv = 1.0f / sum;

    if (n < PN) {
        float* orow = out + ((size_t)bt * PN + n) * PN;
        #pragma unroll
        for (int ct = 0; ct < 19; ++ct) {
            const int m0 = ct * 16 + kq * 4;
            f32x4u o;
            o[0] = acc[ct][0] * inv; o[1] = acc[ct][1] * inv;
            o[2] = acc[ct][2] * inv; o[3] = acc[ct][3] * inv;
            *(f32x4u*)(orow + m0) = o;
        }
        const int m0 = 304 + kq * 4;              // ct = 19 tail
        #pragma unroll
        for (int r = 0; r < 4; ++r)
            if (m0 + r < PN) orow[m0 + r] = acc[19][r] * inv;
    }
}

extern "C" void kernel_launch(void* const* d_in, const int* in_sizes, int n_in,
                              void* d_out, int out_size, void* d_ws, size_t ws_size,
                              hipStream_t stream) {
    const float* x  = (const float*)d_in[0];
    const int* mask = (const int*)d_in[1];
    const float* Wq = (const float*)d_in[2];
    const float* bq = (const float*)d_in[3];
    const float* Wk = (const float*)d_in[4];
    const float* bk = (const float*)d_in[5];
    float* out = (float*)d_out;

    // workspace: qws bf16 [96][320][64], kws bf16 [96][320][64]  (7.86 MB)
    unsigned short* qws = (unsigned short*)d_ws;
    unsigned short* kws = qws + (size_t)96 * NP * 64;

    qk_proj_kernel<<<dim3(96 * 10), dim3(128), 0, stream>>>(x, Wq, bq, Wk, bk, qws, kws);
    attn_kernel<<<dim3(96 * 5), dim3(256), 0, stream>>>(qws, kws, mask, out);
}

// Round 6
// 107.652 us; speedup vs baseline: 1.6494x; 1.0107x over previous
//
#include <hip/hip_runtime.h>
#include <math.h>

// Problem constants
#define PB 8
#define PT 12
#define PN 307
#define NP 320                      // padded N for MFMA tiling
#define SCALE 0.35355339059327373f  // 1/sqrt(8)

typedef short bf16x8 __attribute__((ext_vector_type(8)));
typedef float f32x4  __attribute__((ext_vector_type(4)));
// 4-byte-aligned vectors for rows whose base is only 4B-aligned (307-stride)
typedef int   i32x4u __attribute__((ext_vector_type(4), aligned(4)));
typedef float f32x4u __attribute__((ext_vector_type(4), aligned(4)));

__device__ __forceinline__ unsigned short f32_to_bf16(float v) {
    unsigned u = __float_as_uint(v);
    u += 0x7FFFu + ((u >> 16) & 1u);   // RNE
    return (unsigned short)(u >> 16);
}

__device__ __forceinline__ bf16x8 pack8(float4 lo, float4 hi) {
    bf16x8 r;
    r[0] = (short)f32_to_bf16(lo.x); r[1] = (short)f32_to_bf16(lo.y);
    r[2] = (short)f32_to_bf16(lo.z); r[3] = (short)f32_to_bf16(lo.w);
    r[4] = (short)f32_to_bf16(hi.x); r[5] = (short)f32_to_bf16(hi.y);
    r[6] = (short)f32_to_bf16(hi.z); r[7] = (short)f32_to_bf16(hi.w);
    return r;
}

// ---------------------------------------------------------------------------
// Kernel A v5 (MFMA projection, no LDS/barriers, e-split across waves):
// Grid: 96 bt * 10 chunks of 32 n = 960 blocks; block 256 = 4 waves.
// Wave (wn, we): n-tile = chunk*32 + wn*16, e-range = we*32 (2 et-tiles).
// -> 3840 waves (15/CU), per-wave chain: 16 x-gather loads + 8 MFMAs.
// ---------------------------------------------------------------------------
__global__ __launch_bounds__(256) void qk_proj_kernel(
    const float* __restrict__ x,
    const float* __restrict__ Wq, const float* __restrict__ bq,
    const float* __restrict__ Wk, const float* __restrict__ bk,
    unsigned short* __restrict__ qws, unsigned short* __restrict__ kws)
{
    const int tid  = threadIdx.x;
    const int lane = tid & 63;
    const int wv   = tid >> 6;
    const int wn   = wv & 1;
    const int we   = wv >> 1;
    const int chunk = blockIdx.x % 10;
    const int bt    = blockIdx.x / 10;
    const int b = bt / PT, t = bt % PT;
    const int rlo = lane & 15;
    const int kq  = lane >> 4;
    const int n0  = chunk * 32 + wn * 16;        // wave's n-tile base

    // A fragments: xT[n][c], n = n0+rlo (clamped), c = ks*32+kq*8+j
    const int nn = min(n0 + rlo, PN - 1);
    const float* xrow = x + ((size_t)b * 64 * PT + t) * PN + nn;  // + c*PT*PN
    bf16x8 a[2];
    #pragma unroll
    for (int ks = 0; ks < 2; ++ks) {
        #pragma unroll
        for (int j = 0; j < 8; ++j) {
            const int c = ks * 32 + kq * 8 + j;
            a[ks][j] = (short)f32_to_bf16(xrow[(size_t)c * PT * PN]);
        }
    }

    // B fragments: W rows e = we*32 + eti*16 + rlo (waves share via L1)
    f32x4 accq[2] = {}, acck[2] = {};
    #pragma unroll
    for (int eti = 0; eti < 2; ++eti) {
        const int e_row = we * 32 + eti * 16 + rlo;
        const float* wq_r = Wq + (size_t)e_row * 64 + kq * 8;
        const float* wk_r = Wk + (size_t)e_row * 64 + kq * 8;
        #pragma unroll
        for (int ks = 0; ks < 2; ++ks) {
            const bf16x8 bqf = pack8(*(const float4*)(wq_r + ks * 32),
                                     *(const float4*)(wq_r + ks * 32 + 4));
            const bf16x8 bkf = pack8(*(const float4*)(wk_r + ks * 32),
                                     *(const float4*)(wk_r + ks * 32 + 4));
            accq[eti] = __builtin_amdgcn_mfma_f32_16x16x32_bf16(a[ks], bqf, accq[eti], 0, 0, 0);
            acck[eti] = __builtin_amdgcn_mfma_f32_16x16x32_bf16(a[ks], bkf, acck[eti], 0, 0, 0);
        }
    }

    // Epilogue: bias + bf16 + store. Pad rows (n>=307) never stored; attn
    // masks/discards everything it derives from them.
    #pragma unroll
    for (int eti = 0; eti < 2; ++eti) {
        const int e = we * 32 + eti * 16 + rlo;
        const float bqv = bq[e], bkv = bk[e];
        #pragma unroll
        for (int r = 0; r < 4; ++r) {
            const int n = n0 + kq * 4 + r;
            if (n < PN) {
                qws[((size_t)bt * NP + n) * 64 + e] = f32_to_bf16(accq[eti][r] + bqv);
                kws[((size_t)bt * NP + n) * 64 + e] = f32_to_bf16(acck[eti][r] + bkv);
            }
        }
    }
}

// ---------------------------------------------------------------------------
// Kernel B v4 (swapped-operand attn, m-split across waves):
// Grid: 96 bt * 20 n-tiles = 1920 blocks; block 256 = 4 waves (30 waves/CU).
// All 4 waves share one 16-row n-tile; wave wm owns 5 ct (80 m-columns).
// Lane (nl,kq): n = ng+nl; m = ct*16 + kq*4 + r -> float4 stores, int4 mask.
// Softmax: shfl_xor(16,32) within wave, then 512-B LDS combine across waves.
// ---------------------------------------------------------------------------
__global__ __launch_bounds__(256) void attn_kernel(
    const unsigned short* __restrict__ qws,
    const unsigned short* __restrict__ kws,
    const int* __restrict__ mask,
    float* __restrict__ out)
{
    __shared__ float redmx[4][16];
    __shared__ float redsm[4][16];

    const int tid  = threadIdx.x;
    const int lane = tid & 63;
    const int wm   = tid >> 6;               // m-quarter
    const int ntile = blockIdx.x % 20;
    const int bt    = blockIdx.x / 20;
    const int b     = bt / PT;
    const int ng  = ntile * 16;
    const int nl  = lane & 15;
    const int kq  = lane >> 4;
    const int n   = ng + nl;
    const int nn  = (n < PN) ? n : (PN - 1); // clamp for mask row reads

    // B fragments (Q row n; pad rows are in-bounds garbage, discarded later)
    const bf16x8* qp = (const bf16x8*)(qws + ((size_t)bt * NP + n) * 64 + kq * 8);
    const bf16x8 bq0 = qp[0], bq1 = qp[4];
    // A fragments (K rows of this wave's m-range)
    const unsigned short* kbase = kws + ((size_t)bt * NP + nl) * 64 + kq * 8;

    f32x4 acc[5] = {};
    #pragma unroll
    for (int i = 0; i < 5; ++i) {
        const int ct = wm * 5 + i;
        const unsigned short* kb = kbase + (size_t)ct * 16 * 64;
        const bf16x8 a0 = *(const bf16x8*)(kb);
        const bf16x8 a1 = *(const bf16x8*)(kb + 32);
        acc[i] = __builtin_amdgcn_mfma_f32_16x16x32_bf16(a0, bq0, acc[i], 0, 0, 0);
        acc[i] = __builtin_amdgcn_mfma_f32_16x16x32_bf16(a1, bq1, acc[i], 0, 0, 0);
    }

    // ---- mask + scale, per-lane max over this wave's 20 m-values
    const int* mrow = mask + ((size_t)b * PN + nn) * PN;
    float mx = -INFINITY;
    #pragma unroll
    for (int i = 0; i < 5; ++i) {
        const int ct = wm * 5 + i;
        const int m0 = ct * 16 + kq * 4;
        const i32x4u mv = *(const i32x4u*)(mrow + m0);
        float sv[4];
        sv[0] = mv[0] ? acc[i][0] * SCALE : -1e9f;
        sv[1] = mv[1] ? acc[i][1] * SCALE : -1e9f;
        sv[2] = mv[2] ? acc[i][2] * SCALE : -1e9f;
        sv[3] = mv[3] ? acc[i][3] * SCALE : -1e9f;
        if (ct == 19) {                       // pad columns m >= 307 (wave-uniform)
            #pragma unroll
            for (int r = 0; r < 4; ++r)
                if (m0 + r >= PN) sv[r] = -INFINITY;
        }
        #pragma unroll
        for (int r = 0; r < 4; ++r) { acc[i][r] = sv[r]; mx = fmaxf(mx, sv[r]); }
    }
    mx = fmaxf(mx, __shfl_xor(mx, 16));
    mx = fmaxf(mx, __shfl_xor(mx, 32));
    if (lane < 16) redmx[wm][lane] = mx;
    __syncthreads();
    const float gmx = fmaxf(fmaxf(redmx[0][nl], redmx[1][nl]),
                            fmaxf(redmx[2][nl], redmx[3][nl]));

    float sum = 0.f;
    #pragma unroll
    for (int i = 0; i < 5; ++i) {
        #pragma unroll
        for (int r = 0; r < 4; ++r) {
            const float p = __expf(acc[i][r] - gmx);
            acc[i][r] = p;
            sum += p;
        }
    }
    sum += __shfl_xor(sum, 16);
    sum += __shfl_xor(sum, 32);
    if (lane < 16) redsm[wm][lane] = sum;
    __syncthreads();
    const float inv = 1.0f / (redsm[0][nl] + redsm[1][nl] +
                              redsm[2][nl] + redsm[3][nl]);

    if (n < PN) {
        float* orow = out + ((size_t)bt * PN + n) * PN;
        #pragma unroll
        for (int i = 0; i < 5; ++i) {
            const int ct = wm * 5 + i;
            const int m0 = ct * 16 + kq * 4;
            if (ct < 19) {
                f32x4u o;
                o[0] = acc[i][0] * inv; o[1] = acc[i][1] * inv;
                o[2] = acc[i][2] * inv; o[3] = acc[i][3] * inv;
                *(f32x4u*)(orow + m0) = o;
            } else {
                #pragma unroll
                for (int r = 0; r < 4; ++r)
                    if (m0 + r < PN) orow[m0 + r] = acc[i][r] * inv;
            }
        }
    }
}

extern "C" void kernel_launch(void* const* d_in, const int* in_sizes, int n_in,
                              void* d_out, int out_size, void* d_ws, size_t ws_size,
                              hipStream_t stream) {
    const float* x  = (const float*)d_in[0];
    const int* mask = (const int*)d_in[1];
    const float* Wq = (const float*)d_in[2];
    const float* bq = (const float*)d_in[3];
    const float* Wk = (const float*)d_in[4];
    const float* bk = (const float*)d_in[5];
    float* out = (float*)d_out;

    // workspace: qws bf16 [96][320][64], kws bf16 [96][320][64]  (7.86 MB)
    unsigned short* qws = (unsigned short*)d_ws;
    unsigned short* kws = qws + (size_t)96 * NP * 64;

    qk_proj_kernel<<<dim3(96 * 10), dim3(256), 0, stream>>>(x, Wq, bq, Wk, bk, qws, kws);
    attn_kernel<<<dim3(96 * 20), dim3(256), 0, stream>>>(qws, kws, mask, out);
}